// Round 1
// 3790.172 us; speedup vs baseline: 3.0228x; 3.0228x over previous
//
#include <hip/hip_runtime.h>

#define UU 512
#define EE 300
#define VTT 30000
#define SS 64
#define TT 32
#define BB 32

typedef unsigned short u16;
typedef short s8v __attribute__((ext_vector_type(8)));
typedef unsigned short us4 __attribute__((ext_vector_type(4)));
typedef float f4v __attribute__((ext_vector_type(4)));

__device__ __forceinline__ float bf2f(u16 v){
  union { unsigned u; float f; } x; x.u = ((unsigned)v) << 16; return x.f;
}
__device__ __forceinline__ u16 f2bf(float f){
  union { float f; unsigned u; } x; x.f = f;
  unsigned r = x.u + 0x7FFFu + ((x.u >> 16) & 1u);
  return (u16)(r >> 16);
}
__device__ __forceinline__ float sigm(float x){ return 1.f / (1.f + __expf(-x)); }
__device__ __forceinline__ float ftanh(float x){
  float t = __expf(-2.f * fabsf(x));
  float r = (1.f - t) / (1.f + t);
  return x < 0.f ? -r : r;
}
__device__ __forceinline__ int imin(int a, int b){ return a < b ? a : b; }

// async global->LDS, 16B per lane; LDS dest = wave-uniform base + lane*16
__device__ __forceinline__ void gll16(const u16* g, u16* l){
  __builtin_amdgcn_global_load_lds(
      (const __attribute__((address_space(1))) void*)g,
      (__attribute__((address_space(3))) void*)l, 16, 0, 0);
}

// ---------------- init: zero h, out row 0 (zero_row), Xl pad cols ----------------
__global__ void k_init(float* __restrict__ h, float* __restrict__ out, u16* __restrict__ Xl){
  int i = blockIdx.x * 256 + threadIdx.x;
  if(i < 4*BB*UU) h[i] = 0.f;
  if(i < BB*VTT) out[i] = 0.f;
  if(i < 992*20){
    int r = i / 20, c = i - r*20;
    Xl[(size_t)r*1856 + 1836 + c] = 0;
  }
}

// ---------------- Xsrc[tb][k] = bf16(emb_src[source[tb]][k]), K padded to 320 ----
__global__ void k_embsrc(const float* __restrict__ emb, const int* __restrict__ src,
                         u16* __restrict__ X){
  int i = blockIdx.x * 256 + threadIdx.x;
  if(i >= SS*BB*320) return;
  int tb = i / 320, k = i - tb*320;
  X[i] = (k < EE) ? f2bf(emb[(size_t)src[tb]*EE + k]) : (u16)0;
}

// ---------------- EmbT[t*32+b][k] = bf16(emb_trg[target[t*32+b]][k]), pad 320 ----
__global__ void k_embT(const float* __restrict__ emb, const int* __restrict__ tgt,
                       u16* __restrict__ X){
  int i = blockIdx.x * 256 + threadIdx.x;
  if(i >= 992*320) return;
  int r = i / 320, k = i - r*320;
  X[i] = (k < EE) ? f2bf(emb[(size_t)tgt[r]*EE + k]) : (u16)0;
}

// ---------------- fp32 -> bf16 convert with zero col-pad (take%4==0) -------------
__global__ void k_cvt(const float* __restrict__ src, int srs, int cofs, int take,
                      u16* __restrict__ dst, int cdst){
  int r = blockIdx.x;
  const float* s = src + (size_t)r*srs + cofs;
  u16* d = dst + (size_t)r*cdst;
  for(int c4 = threadIdx.x; c4 < (cdst >> 2); c4 += blockDim.x){
    us4 o;
    if(c4*4 < take){
      f4v v = *(const f4v*)(s + c4*4);
      o[0]=f2bf(v[0]); o[1]=f2bf(v[1]); o[2]=f2bf(v[2]); o[3]=f2bf(v[3]);
    } else o = (us4){0,0,0,0};
    *(us4*)(d + c4*4) = o;
  }
}

// ---------------- bf16xbf16 GEMM-BT: C(M,N)=A(M,K)@B(N,K)^T+bias -----------------
// m97 structure: 128x128 tile, BK=32, global_load_lds w16, linear LDS [128][32]
// requires: K%32==0, lda%8==0, ldb%8==0, A/B 16B-aligned
__global__ __launch_bounds__(256) void k_gemm_bf(
    const u16* __restrict__ A, int lda,
    const u16* __restrict__ B, int ldb,
    const float* __restrict__ bias,
    float* __restrict__ C, int ldc, int mofs,
    int M, int N, int K){
  int m0 = blockIdx.x * 128;
  int n0 = blockIdx.y * 128;
  int tid = threadIdx.x;
  int lane = tid & 63, wave = tid >> 6;
  int wm = wave >> 1, wn = wave & 1;
  int lm = lane & 15, lq = lane >> 4;
  __shared__ __align__(16) u16 Asl[128*32];
  __shared__ __align__(16) u16 Bsl[128*32];
  f4v acc[4][4];
  #pragma unroll
  for(int i = 0; i < 4; i++)
    #pragma unroll
    for(int j = 0; j < 4; j++) acc[i][j] = (f4v){0.f,0.f,0.f,0.f};
  // two 1KB loads per wave per operand; elem offset in tile = (wave*2+j)*512 + lane*8
  int e0 = (wave*2+0)*512 + lane*8;
  int e1 = (wave*2+1)*512 + lane*8;
  int r0 = e0 >> 5, c0 = e0 & 31;
  int r1 = e1 >> 5, c1 = e1 & 31;
  const u16* Ag0 = A + (size_t)imin(m0+r0, M-1)*lda + c0;
  const u16* Ag1 = A + (size_t)imin(m0+r1, M-1)*lda + c1;
  const u16* Bg0 = B + (size_t)imin(n0+r0, N-1)*ldb + c0;
  const u16* Bg1 = B + (size_t)imin(n0+r1, N-1)*ldb + c1;
  u16* Al0 = Asl + (wave*2+0)*512;   // wave-uniform LDS bases
  u16* Al1 = Asl + (wave*2+1)*512;
  u16* Bl0 = Bsl + (wave*2+0)*512;
  u16* Bl1 = Bsl + (wave*2+1)*512;
  for(int k0 = 0; k0 < K; k0 += 32){
    __syncthreads();                 // prior iter's ds_reads done before overwrite
    gll16(Ag0 + k0, Al0); gll16(Ag1 + k0, Al1);
    gll16(Bg0 + k0, Bl0); gll16(Bg1 + k0, Bl1);
    __syncthreads();                 // drains vmcnt -> LDS ready
    s8v af[4], bfv[4];
    #pragma unroll
    for(int mi = 0; mi < 4; mi++)
      af[mi] = *(const s8v*)(Asl + (wm*64 + mi*16 + lm)*32 + lq*8);
    #pragma unroll
    for(int nj = 0; nj < 4; nj++)
      bfv[nj] = *(const s8v*)(Bsl + (wn*64 + nj*16 + lm)*32 + lq*8);
    #pragma unroll
    for(int mi = 0; mi < 4; mi++)
      #pragma unroll
      for(int nj = 0; nj < 4; nj++)
        acc[mi][nj] = __builtin_amdgcn_mfma_f32_16x16x32_bf16(af[mi], bfv[nj], acc[mi][nj], 0, 0, 0);
  }
  #pragma unroll
  for(int nj = 0; nj < 4; nj++){
    int n = n0 + wn*64 + nj*16 + lm;
    if(n < N){
      float bv = bias[n];
      #pragma unroll
      for(int mi = 0; mi < 4; mi++){
        #pragma unroll
        for(int rg = 0; rg < 4; rg++){
          int m = m0 + wm*64 + mi*16 + lq*4 + rg;   // C/D: col=lane&15, row=(lane>>4)*4+reg
          if(m < M) C[(size_t)(m + mofs)*ldc + n] = acc[mi][nj][rg] + bv;
        }
      }
    }
  }
}

// ---------------- legacy GEMM-BT (B fp32, on-the-fly bf16) — ws fallback ---------
__global__ __launch_bounds__(256) void k_bgemm(
    const u16* __restrict__ A, int lda,
    const float* __restrict__ B, int ldb,
    const float* __restrict__ bias,
    float* __restrict__ C, int ldc, int mofs,
    int M, int N, int K){
  int m0 = blockIdx.x * 128;
  int n0 = blockIdx.y * 128;
  int tid = threadIdx.x;
  int lane = tid & 63, wave = tid >> 6;
  int wm = wave >> 1, wn = wave & 1;
  int lm = lane & 15, lq = lane >> 4;
  __shared__ __align__(16) u16 Asl[128*40];
  __shared__ __align__(16) u16 Bsl[128*40];
  f4v acc[4][4];
  #pragma unroll
  for(int i = 0; i < 4; i++)
    #pragma unroll
    for(int j = 0; j < 4; j++) acc[i][j] = (f4v){0.f,0.f,0.f,0.f};
  for(int k0 = 0; k0 < K; k0 += 32){
    __syncthreads();
    #pragma unroll
    for(int p = 0; p < 4; p++){
      int pos = tid + p*256;
      int row = pos >> 3, kc = pos & 7;
      int k = k0 + kc*4;
      bool kok = (k + 4) <= K;
      us4 av = (us4){0,0,0,0};
      if(kok && (m0 + row) < M)
        av = *(const us4*)(A + (size_t)(m0+row)*lda + k);
      *(us4*)(Asl + row*40 + kc*4) = av;
      us4 bq = (us4){0,0,0,0};
      if(kok && (n0 + row) < N){
        f4v bv = *(const f4v*)(B + (size_t)(n0+row)*ldb + k);
        bq[0] = f2bf(bv[0]); bq[1] = f2bf(bv[1]); bq[2] = f2bf(bv[2]); bq[3] = f2bf(bv[3]);
      }
      *(us4*)(Bsl + row*40 + kc*4) = bq;
    }
    __syncthreads();
    s8v af[4], bfv[4];
    #pragma unroll
    for(int mi = 0; mi < 4; mi++)
      af[mi] = *(const s8v*)(Asl + (wm*64 + mi*16 + lm)*40 + lq*8);
    #pragma unroll
    for(int nj = 0; nj < 4; nj++)
      bfv[nj] = *(const s8v*)(Bsl + (wn*64 + nj*16 + lm)*40 + lq*8);
    #pragma unroll
    for(int mi = 0; mi < 4; mi++)
      #pragma unroll
      for(int nj = 0; nj < 4; nj++)
        acc[mi][nj] = __builtin_amdgcn_mfma_f32_16x16x32_bf16(af[mi], bfv[nj], acc[mi][nj], 0, 0, 0);
  }
  #pragma unroll
  for(int nj = 0; nj < 4; nj++){
    int n = n0 + wn*64 + nj*16 + lm;
    if(n < N){
      float bv = bias[n];
      #pragma unroll
      for(int mi = 0; mi < 4; mi++){
        #pragma unroll
        for(int rg = 0; rg < 4; rg++){
          int m = m0 + wm*64 + mi*16 + lq*4 + rg;
          if(m < M) C[(size_t)(m + mofs)*ldc + n] = acc[mi][nj][rg] + bv;
        }
      }
    }
  }
}

// ---------------- one encoder step, both dirs; single-stage LDS ------------------
// 256 blocks x 384 thr: blk = 128 per dir, 4 units x 3 gates per block.
// h staged ONCE (64KB, XOR-swizzled f4v groups -> bank-balanced stride-512 reads)
__global__ __launch_bounds__(384) void k_enc_step(int t,
    const float* __restrict__ gi_f, const float* __restrict__ gi_b,
    const float* __restrict__ Whh_f, const float* __restrict__ bhh_f,
    const float* __restrict__ Whh_b, const float* __restrict__ bhh_b,
    float* __restrict__ h, u16* __restrict__ enc){
  int dir = blockIdx.x >> 7;
  int blk = blockIdx.x & 127;
  int tid = threadIdx.x;
  int b = tid & 31, q = tid >> 5;       // q 0..11
  int g = q % 3, ul = q / 3;
  int u = blk*4 + ul;
  int row = g*512 + u;
  int par = t & 1;
  int te = dir ? (SS-1-t) : t;
  const float* hin  = h + (size_t)(dir*2 + par)     * BB*UU;
  float*       hout = h + (size_t)(dir*2 + (par^1)) * BB*UU;
  const float* Whh = dir ? Whh_b : Whh_f;
  const float* bhh = dir ? bhh_b : bhh_f;
  const float* gi  = (dir ? gi_b : gi_f) + (size_t)(te*BB)*1536;
  __shared__ __align__(16) float hch[32*512];
  __shared__ float accs[12*33];
  for(int i4 = tid; i4 < 4096; i4 += 384){
    int bb = i4 >> 7, e = i4 & 127;
    f4v v = *(const f4v*)(hin + bb*512 + (e << 2));
    *(f4v*)(hch + bb*512 + ((e ^ (bb & 7)) << 2)) = v;
  }
  __syncthreads();
  const float* wr = Whh + (size_t)row*512;
  int pb = b & 7;
  const float* xb = hch + b*512;
  float acc = 0.f;
  #pragma unroll 8
  for(int e = 0; e < 128; e++){
    f4v x = *(const f4v*)(xb + ((e ^ pb) << 2));
    f4v w = *(const f4v*)(wr + (e << 2));
    acc += x[0]*w[0] + x[1]*w[1] + x[2]*w[2] + x[3]*w[3];
  }
  acc += bhh[row];                    // accs holds gh+bhh (gi kept separate for n-gate)
  accs[q*33 + b] = acc;
  __syncthreads();
  if(g == 0){
    const float* gib = gi + b*1536 + u;
    float r  = sigm(gib[0]     + accs[q*33 + b]);
    float z  = sigm(gib[512]   + accs[(q+1)*33 + b]);
    float n  = ftanh(gib[1024] + r * accs[(q+2)*33 + b]);
    float hold = xb[(((u >> 2) ^ pb) << 2) + (u & 3)];
    float h2 = (1.f - z)*n + z*hold;
    hout[b*512 + u] = h2;
    enc[(size_t)(b*SS + te)*1024 + dir*512 + u] = f2bf(h2);
  }
}

// ---------------- state = tanh([hf,hb] @ Wfc^T + bfc) ----------------
__global__ __launch_bounds__(256) void k_encfc(
    const float* __restrict__ h, const float* __restrict__ Wfc,
    const float* __restrict__ bfc, float* __restrict__ st){
  int b = blockIdx.x;
  __shared__ __align__(16) float hc[1024];
  for(int i = threadIdx.x; i < 512; i += 256){
    hc[i]       = h[0*BB*UU + b*UU + i];
    hc[512 + i] = h[2*BB*UU + b*UU + i];
  }
  __syncthreads();
  for(int u = threadIdx.x; u < 512; u += 256){
    const float* w = Wfc + u*1024;
    float a = 0.f;
    for(int k = 0; k < 1024; k += 4){
      f4v x = *(const f4v*)(hc + k);
      f4v wv = *(const f4v*)(w + k);
      a += x[0]*wv[0] + x[1]*wv[1] + x[2]*wv[2] + x[3]*wv[3];
    }
    st[b*UU + u] = ftanh(a + bfc[u]);
  }
}

// ---------------- decoder attention: 32 blocks x 1024 threads --------------------
__global__ __launch_bounds__(1024) void k_dattn(int t,
    const float* __restrict__ st, const float* __restrict__ attn_W,
    const float* __restrict__ P, const u16* __restrict__ enc,
    const float* __restrict__ emb_trg, const int* __restrict__ target,
    float* __restrict__ ctx, u16* __restrict__ Xl){
  int b = blockIdx.x, tid = threadIdx.x;
  __shared__ __align__(16) float sv[512];
  __shared__ float qvt[512];          // q transposed: qvt[(a&31)*16 + (a>>5)]
  __shared__ float wv[64];
  if(tid < 512) sv[tid] = st[b*512 + tid];
  __syncthreads();
  {                                   // q[a] = st . attn_W[a][0:512], 2 thr per a
    int a = tid >> 1, hf = tid & 1;
    const float* w = attn_W + (size_t)a*1536 + hf*256;
    const float* x = sv + hf*256;
    float acc = 0.f;
    #pragma unroll 8
    for(int k4 = 0; k4 < 64; k4++){
      f4v xx = *(const f4v*)(x + (k4 << 2));
      f4v ww = *(const f4v*)(w + (k4 << 2));
      acc += xx[0]*ww[0] + xx[1]*ww[1] + xx[2]*ww[2] + xx[3]*ww[3];
    }
    acc += __shfl_xor(acc, 1);
    if(hf == 0) qvt[(a & 31)*16 + (a >> 5)] = acc;
  }
  __syncthreads();
  {                                   // scores: 16 threads per s, shuffle-reduce
    int s = tid >> 4, part = tid & 15;
    const float* Pb = P + (size_t)(b*SS + s)*512 + part*32;
    float ps = 0.f;
    #pragma unroll
    for(int i = 0; i < 32; i += 4){
      f4v pv = *(const f4v*)(Pb + i);
      ps += ftanh(pv[0] + qvt[(i+0)*16 + part]);
      ps += ftanh(pv[1] + qvt[(i+1)*16 + part]);
      ps += ftanh(pv[2] + qvt[(i+2)*16 + part]);
      ps += ftanh(pv[3] + qvt[(i+3)*16 + part]);
    }
    #pragma unroll
    for(int o = 1; o < 16; o <<= 1) ps += __shfl_xor(ps, o);
    if(part == 0) wv[s] = ps;
  }
  __syncthreads();
  if(tid < 64){                       // softmax over 64 (one wave)
    float sc = wv[tid];
    float m = sc;
    for(int o = 32; o > 0; o >>= 1) m = fmaxf(m, __shfl_xor(m, o));
    float e = __expf(sc - m);
    float ssum = e;
    for(int o = 32; o > 0; o >>= 1) ssum += __shfl_xor(ssum, o);
    wv[tid] = e / ssum;
  }
  __syncthreads();
  int rowX = t*BB + b;
  {                                   // ctx: 1 col per thread
    int j = tid;
    float acc = 0.f;
    const u16* eb = enc + (size_t)(b*SS)*1024 + j;
    #pragma unroll 8
    for(int s2 = 0; s2 < SS; s2++)
      acc += wv[s2] * bf2f(eb[(size_t)s2*1024]);
    ctx[b*1024 + j] = acc;
    Xl[(size_t)rowX*1856 + 512 + j] = f2bf(acc);
  }
  if(tid < EE){
    int tok = target[t*BB + b];
    Xl[(size_t)rowX*1856 + 1536 + tid] = f2bf(emb_trg[(size_t)tok*EE + tid]);
  }
}

// ---------------- decoder GRU step; emb-part precomputed in giE ------------------
// 256 blocks x 192 thr: 128 row-groups (4 units x 3 gates) x 2 batch halves.
// x = [ctx(1024)|st(512)] fp32 staged ONCE per 16-batch half (96KB, XOR-swizzled)
__global__ __launch_bounds__(192) void k_dgru(int t,
    const float* __restrict__ st_in, float* __restrict__ st_out,
    const float* __restrict__ ctx, const float* __restrict__ giE,
    const float* __restrict__ Wih, const float* __restrict__ Whh,
    const float* __restrict__ bhh,
    u16* __restrict__ Xl){
  int rg = blockIdx.x >> 1;
  int bh = blockIdx.x & 1;
  int tid = threadIdx.x;
  int b16 = tid & 15, q = tid >> 4;   // q 0..11
  int g = q % 3, ul = q / 3;
  int u = rg*4 + ul;
  int row = g*512 + u;
  int b = bh*16 + b16;
  __shared__ __align__(16) float xs[16*1536];
  __shared__ float accsA[12*17], accsB[12*17];
  for(int i4 = tid; i4 < 6144; i4 += 192){
    int bb = i4 / 384, e = i4 - bb*384;
    int bg = bh*16 + bb;
    f4v v;
    if(e < 256) v = *(const f4v*)(ctx + bg*1024 + (e << 2));
    else        v = *(const f4v*)(st_in + bg*512 + ((e - 256) << 2));
    *(f4v*)(xs + bb*1536 + ((e ^ (bb & 7)) << 2)) = v;
  }
  __syncthreads();
  const float* wA = Wih + (size_t)row*1324 + 300;   // ctx cols of dec_Wih
  const float* wB = Whh + (size_t)row*512;
  float accA = 0.f, accB = 0.f;
  int pb = b16 & 7;
  const float* xb = xs + b16*1536;
  #pragma unroll 8
  for(int e = 0; e < 256; e++){
    f4v x = *(const f4v*)(xb + ((e ^ pb) << 2));
    f4v w = *(const f4v*)(wA + (e << 2));
    accA += x[0]*w[0] + x[1]*w[1] + x[2]*w[2] + x[3]*w[3];
  }
  #pragma unroll 8
  for(int e2 = 0; e2 < 128; e2++){
    f4v x = *(const f4v*)(xb + (((e2 + 256) ^ pb) << 2));
    f4v w = *(const f4v*)(wB + (e2 << 2));
    accB += x[0]*w[0] + x[1]*w[1] + x[2]*w[2] + x[3]*w[3];
  }
  int xrow = t*BB + b;
  accA += giE[(size_t)xrow*1536 + row];   // emb@Wih^T + bih, precomputed
  accB += bhh[row];
  accsA[q*17 + b16] = accA;
  accsB[q*17 + b16] = accB;
  __syncthreads();
  if(g == 0){
    float r = sigm(accsA[q*17 + b16]     + accsB[q*17 + b16]);
    float z = sigm(accsA[(q+1)*17 + b16] + accsB[(q+1)*17 + b16]);
    float n = ftanh(accsA[(q+2)*17 + b16] + r * accsB[(q+2)*17 + b16]);
    float hold = st_in[b*512 + u];
    float h2 = (1.f - z)*n + z*hold;
    st_out[b*512 + u] = h2;
    Xl[(size_t)xrow*1856 + u] = f2bf(h2);
  }
}

extern "C" void kernel_launch(void* const* d_in, const int* in_sizes, int n_in,
                              void* d_out, int out_size, void* d_ws, size_t ws_size,
                              hipStream_t stream){
  (void)in_sizes; (void)n_in; (void)out_size;
  const float* emb_src = (const float*)d_in[0];
  const float* emb_trg = (const float*)d_in[1];
  const float* eWih_f  = (const float*)d_in[2];
  const float* eWhh_f  = (const float*)d_in[3];
  const float* ebih_f  = (const float*)d_in[4];
  const float* ebhh_f  = (const float*)d_in[5];
  const float* eWih_b  = (const float*)d_in[6];
  const float* eWhh_b  = (const float*)d_in[7];
  const float* ebih_b  = (const float*)d_in[8];
  const float* ebhh_b  = (const float*)d_in[9];
  const float* Wfc     = (const float*)d_in[10];
  const float* bfc     = (const float*)d_in[11];
  const float* attn_W  = (const float*)d_in[12];
  const float* attn_b  = (const float*)d_in[13];
  const float* dWih    = (const float*)d_in[14];
  const float* dWhh    = (const float*)d_in[15];
  const float* dbih    = (const float*)d_in[16];
  const float* dbhh    = (const float*)d_in[17];
  const float* dWfc    = (const float*)d_in[18];
  const float* dbfc    = (const float*)d_in[19];
  const int* source    = (const int*)d_in[20];
  const int* target    = (const int*)d_in[21];
  float* out = (float*)d_out;
  float* wsf = (float*)d_ws;

  // f32 region
  float* gi_f = wsf;                                   // 2048 x 1536
  float* gi_b = gi_f + (size_t)2048*1536;
  float* h    = gi_b + (size_t)2048*1536;              // 2 dirs x 2 parity x 32 x 512
  float* st   = h + 4*BB*UU;                           // 2 parity x 32 x 512
  float* P    = st + 2*BB*UU;                          // 2048 x 512
  float* ctx  = P + (size_t)2048*512;                  // 32 x 1024
  // u16 region (16B aligned: f32 region = 29,884,416 B)
  u16* enc   = (u16*)(ctx + BB*1024);                  // (B,S,2U) bf16
  u16* Xl    = enc + (size_t)2048*1024;                // 992 x 1856 bf16 (K-padded)
  u16* Xsrc  = Xl + (size_t)992*1856;                  // 2048 x 320 bf16
  u16* WihF  = Xsrc + (size_t)2048*320;                // 1536 x 320
  u16* WihB  = WihF + (size_t)1536*320;
  u16* WihE  = WihB + (size_t)1536*320;                // dec_Wih[:, :300] pad
  u16* AttnW = WihE + (size_t)1536*320;                // 512 x 1024
  u16* WfcB  = AttnW + (size_t)512*1024;               // 30000 x 1856 bf16
  u16* EmbT  = Xsrc;                                   // reuse (after gi GEMMs)
  float* giE = gi_f;                                   // reuse (after enc steps)

  bool ws_bf  = ws_size >= 43069504ULL;                // small bf16 weight buffers fit
  bool ws_big = ws_size >= 154429504ULL;               // + 111MB bf16 dWfc fits

  k_init<<<3750, 256, 0, stream>>>(h, out, Xl);
  k_embsrc<<<(SS*BB*320 + 255)/256, 256, 0, stream>>>(emb_src, source, Xsrc);
  if(ws_bf){
    k_cvt<<<1536, 256, 0, stream>>>(eWih_f, 300, 0, 300, WihF, 320);
    k_cvt<<<1536, 256, 0, stream>>>(eWih_b, 300, 0, 300, WihB, 320);
    k_cvt<<<1536, 256, 0, stream>>>(dWih, 1324, 0, 300, WihE, 320);
    k_cvt<<<512, 256, 0, stream>>>(attn_W, 1536, 512, 1024, AttnW, 1024);
    if(ws_big) k_cvt<<<30000, 256, 0, stream>>>(dWfc, 1836, 0, 1836, WfcB, 1856);
    k_gemm_bf<<<dim3(16,12), 256, 0, stream>>>(Xsrc, 320, WihF, 320, ebih_f, gi_f, 1536, 0, 2048, 1536, 320);
    k_gemm_bf<<<dim3(16,12), 256, 0, stream>>>(Xsrc, 320, WihB, 320, ebih_b, gi_b, 1536, 0, 2048, 1536, 320);
  } else {
    k_bgemm<<<dim3(16,12), 256, 0, stream>>>(Xsrc, 320, eWih_f, 300, ebih_f, gi_f, 1536, 0, 2048, 1536, 300);
    k_bgemm<<<dim3(16,12), 256, 0, stream>>>(Xsrc, 320, eWih_b, 300, ebih_b, gi_b, 1536, 0, 2048, 1536, 300);
  }
  for(int t = 0; t < SS; t++)
    k_enc_step<<<256, 384, 0, stream>>>(t, gi_f, gi_b, eWhh_f, ebhh_f, eWhh_b, ebhh_b, h, enc);
  k_encfc<<<BB, 256, 0, stream>>>(h, Wfc, bfc, st);
  if(ws_bf)
    k_gemm_bf<<<dim3(16,4), 256, 0, stream>>>(enc, 1024, AttnW, 1024, attn_b, P, 512, 0, 2048, 512, 1024);
  else
    k_bgemm<<<dim3(16,4), 256, 0, stream>>>(enc, 1024, attn_W + 512, 1536, attn_b, P, 512, 0, 2048, 512, 1024);
  // decoder emb-part gi, hoisted out of the serial loop (includes dbih via bias)
  k_embT<<<(992*320 + 255)/256, 256, 0, stream>>>(emb_trg, target, EmbT);
  if(ws_bf)
    k_gemm_bf<<<dim3(8,12), 256, 0, stream>>>(EmbT, 320, WihE, 320, dbih, giE, 1536, 0, 992, 1536, 320);
  else
    k_bgemm<<<dim3(8,12), 256, 0, stream>>>(EmbT, 320, dWih, 1324, dbih, giE, 1536, 0, 992, 1536, 300);
  for(int t = 0; t < TT-1; t++){
    const float* stin = st + (t & 1) * (BB*UU);
    float* stout      = st + ((t+1) & 1) * (BB*UU);
    k_dattn<<<BB, 1024, 0, stream>>>(t, stin, attn_W, P, enc, emb_trg, target, ctx, Xl);
    k_dgru<<<256, 192, 0, stream>>>(t, stin, stout, ctx, giE, dWih, dWhh, dbhh, Xl);
  }
  // logits rows 32..1023: Xl(992x1856) @ WfcB^T + dbfc
  if(ws_big)
    k_gemm_bf<<<dim3(8,235), 256, 0, stream>>>(Xl, 1856, WfcB, 1856, dbfc, out, VTT, 32, 992, VTT, 1856);
  else
    k_bgemm<<<dim3(8,235), 256, 0, stream>>>(Xl, 1856, dWfc, 1836, dbfc, out, VTT, 32, 992, VTT, 1836);
}

// Round 2
// 2204.876 us; speedup vs baseline: 5.1962x; 1.7190x over previous
//
#include <hip/hip_runtime.h>

#define UU 512
#define EE 300
#define VTT 30000
#define SS 64
#define TT 32
#define BB 32

typedef unsigned short u16;
typedef short s8v __attribute__((ext_vector_type(8)));
typedef unsigned short us4 __attribute__((ext_vector_type(4)));
typedef float f4v __attribute__((ext_vector_type(4)));

__device__ __forceinline__ float bf2f(u16 v){
  union { unsigned u; float f; } x; x.u = ((unsigned)v) << 16; return x.f;
}
__device__ __forceinline__ u16 f2bf(float f){
  union { float f; unsigned u; } x; x.f = f;
  unsigned r = x.u + 0x7FFFu + ((x.u >> 16) & 1u);
  return (u16)(r >> 16);
}
__device__ __forceinline__ float sigm(float x){ return 1.f / (1.f + __expf(-x)); }
__device__ __forceinline__ float ftanh(float x){
  float t = __expf(-2.f * fabsf(x));
  float r = (1.f - t) / (1.f + t);
  return x < 0.f ? -r : r;
}
__device__ __forceinline__ int imin(int a, int b){ return a < b ? a : b; }

// async global->LDS, 16B per lane; LDS dest = wave-uniform base + lane*16B
__device__ __forceinline__ void gll16(const u16* g, u16* l){
  __builtin_amdgcn_global_load_lds(
      (const __attribute__((address_space(1))) void*)g,
      (__attribute__((address_space(3))) void*)l, 16, 0, 0);
}

// ---------------- init: zero hF, out row0, Xl pad cols, hbf ----------------
__global__ void k_init(float* __restrict__ hF, float* __restrict__ out,
                       u16* __restrict__ Xl, float* __restrict__ hbfF){
  int i = blockIdx.x * 256 + threadIdx.x;
  if(i < 4*BB*UU) hF[i] = 0.f;
  if(i < BB*VTT) out[i] = 0.f;
  if(i < 992*20){
    int r = i / 20, c = i - r*20;
    Xl[(size_t)r*1856 + 1836 + c] = 0;
  }
  if(i < 65536) hbfF[i] = 0.f;
}

// ---------------- Xsrc[tb][k] = bf16(emb_src[source[tb]][k]), K padded to 320 ----
__global__ void k_embsrc(const float* __restrict__ emb, const int* __restrict__ src,
                         u16* __restrict__ X){
  int i = blockIdx.x * 256 + threadIdx.x;
  if(i >= SS*BB*320) return;
  int tb = i / 320, k = i - tb*320;
  X[i] = (k < EE) ? f2bf(emb[(size_t)src[tb]*EE + k]) : (u16)0;
}

// ---------------- EmbT + Xl emb cols ----------------
__global__ void k_embT(const float* __restrict__ emb, const int* __restrict__ tgt,
                       u16* __restrict__ X, u16* __restrict__ Xl){
  int i = blockIdx.x * 256 + threadIdx.x;
  if(i >= 992*320) return;
  int r = i / 320, k = i - r*320;
  u16 v = (k < EE) ? f2bf(emb[(size_t)tgt[r]*EE + k]) : (u16)0;
  X[i] = v;
  if(k < EE) Xl[(size_t)r*1856 + 1536 + k] = v;
}

// ---------------- fp32 -> bf16 convert with zero col-pad (take%4==0) -------------
__global__ void k_cvt(const float* __restrict__ src, int srs, int cofs, int take,
                      u16* __restrict__ dst, int cdst){
  int r = blockIdx.x;
  const float* s = src + (size_t)r*srs + cofs;
  u16* d = dst + (size_t)r*cdst;
  for(int c4 = threadIdx.x; c4 < (cdst >> 2); c4 += blockDim.x){
    us4 o;
    if(c4*4 < take){
      f4v v = *(const f4v*)(s + c4*4);
      o[0]=f2bf(v[0]); o[1]=f2bf(v[1]); o[2]=f2bf(v[2]); o[3]=f2bf(v[3]);
    } else o = (us4){0,0,0,0};
    *(us4*)(d + c4*4) = o;
  }
}

// ---------------- weight prep: fragment-linear hi/lo bf16 pack -------------------
// out[((((ub*NKF+kf)*ng+g)*passes+p)*64+l)*8+e] =
//   bf16_hi/lo( W[g*gstr + ub*ubstr + (l&15)][colofs + kf*32 + (l>>4)*8 + e] )
__global__ void k_wprep(const float* __restrict__ W, int ldw, int colofs,
                        int gstr, int ng, int ubstr, int NKF, int passes,
                        int total, u16* __restrict__ out){
  int flat = blockIdx.x * 256 + threadIdx.x;
  if(flat >= total) return;
  int l = flat & 63;
  int g = (flat >> 6) % ng;
  int kf = (flat / (64*ng)) % NKF;
  int ub = flat / (64*ng*NKF);
  int row = g*gstr + ub*ubstr + (l & 15);
  int col = colofs + kf*32 + ((l >> 4) << 3);
  const float* s = W + (size_t)row*ldw + col;
  f4v v0 = *(const f4v*)(s);
  f4v v1 = *(const f4v*)(s + 4);
  size_t base = ((((size_t)(ub*NKF + kf)*ng + g)*passes)*64 + l)*8;
  us4 h0, h1;
  h0[0]=f2bf(v0[0]); h0[1]=f2bf(v0[1]); h0[2]=f2bf(v0[2]); h0[3]=f2bf(v0[3]);
  h1[0]=f2bf(v1[0]); h1[1]=f2bf(v1[1]); h1[2]=f2bf(v1[2]); h1[3]=f2bf(v1[3]);
  *(us4*)(out + base) = h0;
  *(us4*)(out + base + 4) = h1;
  if(passes == 2){
    us4 l0, l1;
    l0[0]=f2bf(v0[0]-bf2f(h0[0])); l0[1]=f2bf(v0[1]-bf2f(h0[1]));
    l0[2]=f2bf(v0[2]-bf2f(h0[2])); l0[3]=f2bf(v0[3]-bf2f(h0[3]));
    l1[0]=f2bf(v1[0]-bf2f(h1[0])); l1[1]=f2bf(v1[1]-bf2f(h1[1]));
    l1[2]=f2bf(v1[2]-bf2f(h1[2])); l1[3]=f2bf(v1[3]-bf2f(h1[3]));
    *(us4*)(out + base + 512) = l0;
    *(us4*)(out + base + 516) = l1;
  }
}

// ---------------- bf16xbf16 GEMM-BT body (m97 structure) -------------------------
__device__ __forceinline__ void gemm_body(int m0, int n0,
    const u16* __restrict__ A, int lda,
    const u16* __restrict__ B, int ldb,
    const float* __restrict__ bias,
    float* __restrict__ C, int ldc, int mofs,
    int M, int N, int K){
  int tid = threadIdx.x;
  int lane = tid & 63, wave = tid >> 6;
  int wm = wave >> 1, wn = wave & 1;
  int lm = lane & 15, lq = lane >> 4;
  __shared__ __align__(16) u16 Asl[128*32];
  __shared__ __align__(16) u16 Bsl[128*32];
  f4v acc[4][4];
  #pragma unroll
  for(int i = 0; i < 4; i++)
    #pragma unroll
    for(int j = 0; j < 4; j++) acc[i][j] = (f4v){0.f,0.f,0.f,0.f};
  int e0 = (wave*2+0)*512 + lane*8;
  int e1 = (wave*2+1)*512 + lane*8;
  int r0 = e0 >> 5, c0 = e0 & 31;
  int r1 = e1 >> 5, c1 = e1 & 31;
  const u16* Ag0 = A + (size_t)imin(m0+r0, M-1)*lda + c0;
  const u16* Ag1 = A + (size_t)imin(m0+r1, M-1)*lda + c1;
  const u16* Bg0 = B + (size_t)imin(n0+r0, N-1)*ldb + c0;
  const u16* Bg1 = B + (size_t)imin(n0+r1, N-1)*ldb + c1;
  u16* Al0 = Asl + (wave*2+0)*512;
  u16* Al1 = Asl + (wave*2+1)*512;
  u16* Bl0 = Bsl + (wave*2+0)*512;
  u16* Bl1 = Bsl + (wave*2+1)*512;
  for(int k0 = 0; k0 < K; k0 += 32){
    __syncthreads();
    gll16(Ag0 + k0, Al0); gll16(Ag1 + k0, Al1);
    gll16(Bg0 + k0, Bl0); gll16(Bg1 + k0, Bl1);
    __syncthreads();
    s8v af[4], bfv[4];
    #pragma unroll
    for(int mi = 0; mi < 4; mi++)
      af[mi] = *(const s8v*)(Asl + (wm*64 + mi*16 + lm)*32 + lq*8);
    #pragma unroll
    for(int nj = 0; nj < 4; nj++)
      bfv[nj] = *(const s8v*)(Bsl + (wn*64 + nj*16 + lm)*32 + lq*8);
    #pragma unroll
    for(int mi = 0; mi < 4; mi++)
      #pragma unroll
      for(int nj = 0; nj < 4; nj++)
        acc[mi][nj] = __builtin_amdgcn_mfma_f32_16x16x32_bf16(af[mi], bfv[nj], acc[mi][nj], 0, 0, 0);
  }
  #pragma unroll
  for(int nj = 0; nj < 4; nj++){
    int n = n0 + wn*64 + nj*16 + lm;
    if(n < N){
      float bv = bias[n];
      #pragma unroll
      for(int mi = 0; mi < 4; mi++){
        #pragma unroll
        for(int rg = 0; rg < 4; rg++){
          int m = m0 + wm*64 + mi*16 + lq*4 + rg;
          if(m < M) C[(size_t)(m + mofs)*ldc + n] = acc[mi][nj][rg] + bv;
        }
      }
    }
  }
}

__global__ __launch_bounds__(256) void k_gemm_bf(
    const u16* __restrict__ A, int lda, const u16* __restrict__ B, int ldb,
    const float* __restrict__ bias, float* __restrict__ C, int ldc, int mofs,
    int M, int N, int K){
  gemm_body(blockIdx.x*128, blockIdx.y*128, A, lda, B, ldb, bias, C, ldc, mofs, M, N, K);
}

// logits GEMM: 1D grid, XCD-bijective swizzle — the 8 m-blocks of each n-panel
// share id%8 (same XCD) and are adjacent in that XCD's dispatch order.
__global__ __launch_bounds__(256) void k_gemm_lg(
    const u16* __restrict__ A, int lda, const u16* __restrict__ B, int ldb,
    const float* __restrict__ bias, float* __restrict__ C, int ldc, int mofs,
    int M, int N, int K){
  int id = blockIdx.x;
  int x = id & 7, j = id >> 3;
  int m = j & 7, p = (j & ~7) | x;
  if(p * 128 >= N) return;
  gemm_body(m*128, p*128, A, lda, B, ldb, bias, C, ldc, mofs, M, N, K);
}

// ---------------- encoder step: MFMA, 64 blocks x 1 wave -------------------------
// block = (dir, ub): 16 units x 3 gates = 48 rows, M=32 batch, K=512 (2 chunks)
__global__ __launch_bounds__(64) void k_encs(int t,
    const float* __restrict__ gi_f, const float* __restrict__ gi_b,
    const u16* __restrict__ Wenc,
    const float* __restrict__ bhh_f, const float* __restrict__ bhh_b,
    float* __restrict__ hF, u16* __restrict__ hbf, u16* __restrict__ enc){
  int dir = blockIdx.x >> 5;
  int ub  = blockIdx.x & 31;
  int l = threadIdx.x;
  int par = t & 1;
  int te = dir ? (SS-1-t) : t;
  const float* gi  = (dir ? gi_b : gi_f) + (size_t)(te*BB)*1536;
  const float* bhh = dir ? bhh_b : bhh_f;
  const u16* Wslab = Wenc + ((size_t)(dir*32 + ub))*49152;
  const u16* Asrc  = hbf + (size_t)(par*2 + dir)*32768;
  u16* Adst        = hbf + (size_t)((par^1)*2 + dir)*32768;
  const float* hin = hF + (size_t)(dir*2 + par)*(BB*UU);
  float* hout      = hF + (size_t)(dir*2 + (par^1))*(BB*UU);
  __shared__ __align__(16) u16 Ab[16384];
  __shared__ __align__(16) u16 Bb[24576];
  f4v acc[2][3];
  #pragma unroll
  for(int i = 0; i < 2; i++)
    #pragma unroll
    for(int j = 0; j < 3; j++) acc[i][j] = (f4v){0.f,0.f,0.f,0.f};
  for(int c = 0; c < 2; c++){
    __syncthreads();
    #pragma unroll
    for(int i = 0; i < 32; i++) gll16(Asrc + c*16384 + i*512 + l*8, Ab + i*512);
    #pragma unroll
    for(int i = 0; i < 48; i++) gll16(Wslab + c*24576 + i*512 + l*8, Bb + i*512);
    __syncthreads();
    #pragma unroll
    for(int kf = 0; kf < 8; kf++){
      s8v a[2][2], bw[3][2];
      #pragma unroll
      for(int mf = 0; mf < 2; mf++)
        #pragma unroll
        for(int p = 0; p < 2; p++)
          a[mf][p] = *(const s8v*)(Ab + ((kf*2+mf)*2+p)*512 + l*8);
      #pragma unroll
      for(int g = 0; g < 3; g++)
        #pragma unroll
        for(int p = 0; p < 2; p++)
          bw[g][p] = *(const s8v*)(Bb + ((kf*3+g)*2+p)*512 + l*8);
      #pragma unroll
      for(int mf = 0; mf < 2; mf++)
        #pragma unroll
        for(int g = 0; g < 3; g++){
          acc[mf][g] = __builtin_amdgcn_mfma_f32_16x16x32_bf16(a[mf][0], bw[g][0], acc[mf][g], 0, 0, 0);
          acc[mf][g] = __builtin_amdgcn_mfma_f32_16x16x32_bf16(a[mf][1], bw[g][0], acc[mf][g], 0, 0, 0);
          acc[mf][g] = __builtin_amdgcn_mfma_f32_16x16x32_bf16(a[mf][0], bw[g][1], acc[mf][g], 0, 0, 0);
        }
    }
  }
  float* ghs = (float*)Ab;              // 48x32 f32 = 6KB, A dead now
  int lm = l & 15, lq = l >> 4;
  #pragma unroll
  for(int mf = 0; mf < 2; mf++)
    #pragma unroll
    for(int g = 0; g < 3; g++)
      #pragma unroll
      for(int rg = 0; rg < 4; rg++)
        ghs[(g*16 + lm)*32 + mf*16 + lq*4 + rg] = acc[mf][g][rg];
  __syncthreads();
  #pragma unroll
  for(int it = 0; it < 8; it++){
    int idx = it*64 + l;
    int b = idx & 31, ulu = idx >> 5;
    int u = ub*16 + ulu;
    float ghr = ghs[(ulu)*32 + b]      + bhh[u];
    float ghz = ghs[(16 + ulu)*32 + b] + bhh[512 + u];
    float ghn = ghs[(32 + ulu)*32 + b] + bhh[1024 + u];
    const float* gb = gi + b*1536 + u;
    float r = sigm(gb[0] + ghr);
    float z = sigm(gb[512] + ghz);
    float n = ftanh(gb[1024] + r*ghn);
    float hold = hin[b*512 + u];
    float h2 = (1.f - z)*n + z*hold;
    hout[b*512 + u] = h2;
    enc[(size_t)(b*SS + te)*1024 + dir*512 + u] = f2bf(h2);
    u16 hi = f2bf(h2);
    float lo = h2 - bf2f(hi);
    int kf = u >> 5, mf = b >> 4, l2 = ((u >> 3) & 3)*16 + (b & 15), e = u & 7;
    int base = ((kf*2 + mf)*2)*512 + l2*8 + e;
    Adst[base]       = hi;
    Adst[base + 512] = f2bf(lo);
  }
}

// ---------------- state = tanh([hf,hb] @ Wfc^T + bfc); also packs Ast[par0] ------
__global__ __launch_bounds__(256) void k_encfc(
    const float* __restrict__ h, const float* __restrict__ Wfc,
    const float* __restrict__ bfc, float* __restrict__ st, u16* __restrict__ Ast0){
  int b = blockIdx.x;
  __shared__ __align__(16) float hc[1024];
  for(int i = threadIdx.x; i < 512; i += 256){
    hc[i]       = h[0*BB*UU + b*UU + i];
    hc[512 + i] = h[2*BB*UU + b*UU + i];
  }
  __syncthreads();
  for(int u = threadIdx.x; u < 512; u += 256){
    const float* w = Wfc + u*1024;
    float a = 0.f;
    for(int k = 0; k < 1024; k += 4){
      f4v x = *(const f4v*)(hc + k);
      f4v wv = *(const f4v*)(w + k);
      a += x[0]*wv[0] + x[1]*wv[1] + x[2]*wv[2] + x[3]*wv[3];
    }
    float sv = ftanh(a + bfc[u]);
    st[b*UU + u] = sv;
    u16 hi = f2bf(sv);
    float lo = sv - bf2f(hi);
    int kf = u >> 5, mf = b >> 4, l2 = ((u >> 3) & 3)*16 + (b & 15), e = u & 7;
    int base = ((kf*2 + mf)*2)*512 + l2*8 + e;
    Ast0[base]       = hi;
    Ast0[base + 512] = f2bf(lo);
  }
}

// ---------------- decoder q: q = st @ attn_W[:, :512]^T, 16 blocks x 1 wave ------
__global__ __launch_bounds__(64) void k_dq(
    const u16* __restrict__ Ast_in, const u16* __restrict__ Wqp,
    float* __restrict__ qG){
  int ub = blockIdx.x;
  int l = threadIdx.x;
  const u16* Ws = Wqp + (size_t)ub*32768;
  __shared__ __align__(16) u16 Ab[16384];
  __shared__ __align__(16) u16 Bb[16384];
  f4v acc[2][2];
  #pragma unroll
  for(int i = 0; i < 2; i++)
    #pragma unroll
    for(int j = 0; j < 2; j++) acc[i][j] = (f4v){0.f,0.f,0.f,0.f};
  for(int c = 0; c < 2; c++){
    __syncthreads();
    #pragma unroll
    for(int i = 0; i < 32; i++) gll16(Ast_in + c*16384 + i*512 + l*8, Ab + i*512);
    #pragma unroll
    for(int i = 0; i < 32; i++) gll16(Ws + c*16384 + i*512 + l*8, Bb + i*512);
    __syncthreads();
    #pragma unroll
    for(int kf = 0; kf < 8; kf++){
      s8v a[2][2], bw[2][2];
      #pragma unroll
      for(int mf = 0; mf < 2; mf++)
        #pragma unroll
        for(int p = 0; p < 2; p++){
          a[mf][p]  = *(const s8v*)(Ab + ((kf*2+mf)*2+p)*512 + l*8);
          bw[mf][p] = *(const s8v*)(Bb + ((kf*2+mf)*2+p)*512 + l*8);
        }
      #pragma unroll
      for(int mf = 0; mf < 2; mf++)
        #pragma unroll
        for(int g = 0; g < 2; g++){
          acc[mf][g] = __builtin_amdgcn_mfma_f32_16x16x32_bf16(a[mf][0], bw[g][0], acc[mf][g], 0, 0, 0);
          acc[mf][g] = __builtin_amdgcn_mfma_f32_16x16x32_bf16(a[mf][1], bw[g][0], acc[mf][g], 0, 0, 0);
          acc[mf][g] = __builtin_amdgcn_mfma_f32_16x16x32_bf16(a[mf][0], bw[g][1], acc[mf][g], 0, 0, 0);
        }
    }
  }
  int lm = l & 15, lq = l >> 4;
  #pragma unroll
  for(int mf = 0; mf < 2; mf++)
    #pragma unroll
    for(int g = 0; g < 2; g++)
      #pragma unroll
      for(int rg = 0; rg < 4; rg++){
        int a_ = ub*32 + g*16 + lm;
        int b  = mf*16 + lq*4 + rg;
        qG[b*512 + (a_ & 31)*16 + (a_ >> 5)] = acc[mf][g][rg];
      }
}

// ---------------- decoder attention: scores/softmax/ctx, 32 blocks x 1024 --------
__global__ __launch_bounds__(1024) void k_dattn(int t,
    const float* __restrict__ qG, const float* __restrict__ P,
    const u16* __restrict__ enc, u16* __restrict__ Actx, u16* __restrict__ Xl){
  int b = blockIdx.x, tid = threadIdx.x;
  __shared__ float qvt[512];
  __shared__ float wv[64];
  if(tid < 512) qvt[tid] = qG[b*512 + tid];
  __syncthreads();
  {
    int s = tid >> 4, part = tid & 15;
    const float* Pb = P + (size_t)(b*SS + s)*512 + part*32;
    float ps = 0.f;
    #pragma unroll
    for(int i = 0; i < 32; i += 4){
      f4v pv = *(const f4v*)(Pb + i);
      ps += ftanh(pv[0] + qvt[(i+0)*16 + part]);
      ps += ftanh(pv[1] + qvt[(i+1)*16 + part]);
      ps += ftanh(pv[2] + qvt[(i+2)*16 + part]);
      ps += ftanh(pv[3] + qvt[(i+3)*16 + part]);
    }
    #pragma unroll
    for(int o = 1; o < 16; o <<= 1) ps += __shfl_xor(ps, o);
    if(part == 0) wv[s] = ps;
  }
  __syncthreads();
  if(tid < 64){
    float sc = wv[tid];
    float m = sc;
    for(int o = 32; o > 0; o >>= 1) m = fmaxf(m, __shfl_xor(m, o));
    float e = __expf(sc - m);
    float ssum = e;
    for(int o = 32; o > 0; o >>= 1) ssum += __shfl_xor(ssum, o);
    wv[tid] = e / ssum;
  }
  __syncthreads();
  int rowX = t*BB + b;
  int j = tid;
  float acc = 0.f;
  const u16* eb = enc + (size_t)(b*SS)*1024 + j;
  #pragma unroll 8
  for(int s2 = 0; s2 < SS; s2++)
    acc += wv[s2] * bf2f(eb[(size_t)s2*1024]);
  u16 cb = f2bf(acc);
  Xl[(size_t)rowX*1856 + 512 + j] = cb;
  int kf = j >> 5, mf = b >> 4, l2 = ((j >> 3) & 3)*16 + (b & 15), e = j & 7;
  Actx[(size_t)(kf*2 + mf)*512 + l2*8 + e] = cb;
}

// ---------------- decoder GRU: MFMA, 32 blocks x 1 wave --------------------------
// block = ub: 16 units x 3 gates; K = ctx(1024,1-pass) + st(512,3-pass hi/lo)
__global__ __launch_bounds__(64) void k_dgru(int t,
    const float* __restrict__ st_in, float* __restrict__ st_out,
    const u16* __restrict__ Actx, const u16* __restrict__ Ast_in,
    u16* __restrict__ Ast_out,
    const u16* __restrict__ Wdc, const u16* __restrict__ Wds,
    const float* __restrict__ giE, const float* __restrict__ bhh,
    u16* __restrict__ Xl){
  int ub = blockIdx.x;
  int l = threadIdx.x;
  const u16* Wdcs = Wdc + (size_t)ub*49152;
  const u16* Wdss = Wds + (size_t)ub*49152;
  __shared__ __align__(16) u16 Ab[16384];
  __shared__ __align__(16) u16 Bb[24576];
  f4v accI[2][3], accH[2][3];
  #pragma unroll
  for(int i = 0; i < 2; i++)
    #pragma unroll
    for(int j = 0; j < 3; j++){
      accI[i][j] = (f4v){0.f,0.f,0.f,0.f};
      accH[i][j] = (f4v){0.f,0.f,0.f,0.f};
    }
  // phases 0,1: ctx (single-pass bf16)
  for(int c = 0; c < 2; c++){
    __syncthreads();
    #pragma unroll
    for(int i = 0; i < 32; i++) gll16(Actx + c*16384 + i*512 + l*8, Ab + i*512);
    #pragma unroll
    for(int i = 0; i < 48; i++) gll16(Wdcs + c*24576 + i*512 + l*8, Bb + i*512);
    __syncthreads();
    #pragma unroll
    for(int kf = 0; kf < 16; kf++){
      s8v a[2], bw[3];
      #pragma unroll
      for(int mf = 0; mf < 2; mf++)
        a[mf] = *(const s8v*)(Ab + (kf*2+mf)*512 + l*8);
      #pragma unroll
      for(int g = 0; g < 3; g++)
        bw[g] = *(const s8v*)(Bb + (kf*3+g)*512 + l*8);
      #pragma unroll
      for(int mf = 0; mf < 2; mf++)
        #pragma unroll
        for(int g = 0; g < 3; g++)
          accI[mf][g] = __builtin_amdgcn_mfma_f32_16x16x32_bf16(a[mf], bw[g], accI[mf][g], 0, 0, 0);
    }
  }
  // phases 2,3: st (hi/lo 3-pass)
  for(int c = 0; c < 2; c++){
    __syncthreads();
    #pragma unroll
    for(int i = 0; i < 32; i++) gll16(Ast_in + c*16384 + i*512 + l*8, Ab + i*512);
    #pragma unroll
    for(int i = 0; i < 48; i++) gll16(Wdss + c*24576 + i*512 + l*8, Bb + i*512);
    __syncthreads();
    #pragma unroll
    for(int kf = 0; kf < 8; kf++){
      s8v a[2][2], bw[3][2];
      #pragma unroll
      for(int mf = 0; mf < 2; mf++)
        #pragma unroll
        for(int p = 0; p < 2; p++)
          a[mf][p] = *(const s8v*)(Ab + ((kf*2+mf)*2+p)*512 + l*8);
      #pragma unroll
      for(int g = 0; g < 3; g++)
        #pragma unroll
        for(int p = 0; p < 2; p++)
          bw[g][p] = *(const s8v*)(Bb + ((kf*3+g)*2+p)*512 + l*8);
      #pragma unroll
      for(int mf = 0; mf < 2; mf++)
        #pragma unroll
        for(int g = 0; g < 3; g++){
          accH[mf][g] = __builtin_amdgcn_mfma_f32_16x16x32_bf16(a[mf][0], bw[g][0], accH[mf][g], 0, 0, 0);
          accH[mf][g] = __builtin_amdgcn_mfma_f32_16x16x32_bf16(a[mf][1], bw[g][0], accH[mf][g], 0, 0, 0);
          accH[mf][g] = __builtin_amdgcn_mfma_f32_16x16x32_bf16(a[mf][0], bw[g][1], accH[mf][g], 0, 0, 0);
        }
    }
  }
  float* ghsI = (float*)Ab;             // 48x32 each, 12KB total
  float* ghsH = ghsI + 1536;
  int lm = l & 15, lq = l >> 4;
  #pragma unroll
  for(int mf = 0; mf < 2; mf++)
    #pragma unroll
    for(int g = 0; g < 3; g++)
      #pragma unroll
      for(int rg = 0; rg < 4; rg++){
        int o = (g*16 + lm)*32 + mf*16 + lq*4 + rg;
        ghsI[o] = accI[mf][g][rg];
        ghsH[o] = accH[mf][g][rg];
      }
  __syncthreads();
  #pragma unroll
  for(int it = 0; it < 8; it++){
    int idx = it*64 + l;
    int b = idx & 31, ulu = idx >> 5;
    int u = ub*16 + ulu;
    int xrow = t*BB + b;
    const float* ge = giE + (size_t)xrow*1536 + u;
    float gIr = ghsI[(ulu)*32 + b]      + ge[0];
    float gIz = ghsI[(16 + ulu)*32 + b] + ge[512];
    float gIn = ghsI[(32 + ulu)*32 + b] + ge[1024];
    float gHr = ghsH[(ulu)*32 + b]      + bhh[u];
    float gHz = ghsH[(16 + ulu)*32 + b] + bhh[512 + u];
    float gHn = ghsH[(32 + ulu)*32 + b] + bhh[1024 + u];
    float r = sigm(gIr + gHr);
    float z = sigm(gIz + gHz);
    float n = ftanh(gIn + r*gHn);
    float hold = st_in[b*512 + u];
    float h2 = (1.f - z)*n + z*hold;
    st_out[b*512 + u] = h2;
    Xl[(size_t)xrow*1856 + u] = f2bf(h2);
    u16 hi = f2bf(h2);
    float lo = h2 - bf2f(hi);
    int kf = u >> 5, mf = b >> 4, l2 = ((u >> 3) & 3)*16 + (b & 15), e = u & 7;
    int base = ((kf*2 + mf)*2)*512 + l2*8 + e;
    Ast_out[base]       = hi;
    Ast_out[base + 512] = f2bf(lo);
  }
}

extern "C" void kernel_launch(void* const* d_in, const int* in_sizes, int n_in,
                              void* d_out, int out_size, void* d_ws, size_t ws_size,
                              hipStream_t stream){
  (void)in_sizes; (void)n_in; (void)out_size; (void)ws_size;
  const float* emb_src = (const float*)d_in[0];
  const float* emb_trg = (const float*)d_in[1];
  const float* eWih_f  = (const float*)d_in[2];
  const float* eWhh_f  = (const float*)d_in[3];
  const float* ebih_f  = (const float*)d_in[4];
  const float* ebhh_f  = (const float*)d_in[5];
  const float* eWih_b  = (const float*)d_in[6];
  const float* eWhh_b  = (const float*)d_in[7];
  const float* ebih_b  = (const float*)d_in[8];
  const float* ebhh_b  = (const float*)d_in[9];
  const float* Wfc     = (const float*)d_in[10];
  const float* bfc     = (const float*)d_in[11];
  const float* attn_W  = (const float*)d_in[12];
  const float* attn_b  = (const float*)d_in[13];
  const float* dWih    = (const float*)d_in[14];
  const float* dWhh    = (const float*)d_in[15];
  const float* dbih    = (const float*)d_in[16];
  const float* dbhh    = (const float*)d_in[17];
  const float* dWfc    = (const float*)d_in[18];
  const float* dbfc    = (const float*)d_in[19];
  const int* source    = (const int*)d_in[20];
  const int* target    = (const int*)d_in[21];
  float* out = (float*)d_out;
  float* wsf = (float*)d_ws;

  // ---- f32 prefix ----
  float* P    = wsf;                                   // 2048x512
  float* hF   = P + (size_t)2048*512;                  // 2dir x 2par x 32 x 512
  float* st   = hF + 65536;                            // 2par x 32 x 512
  float* qG   = st + 32768;                            // 32x512 (permuted)
  float* giE  = qG + 16384;                            // 992x1536
  // ---- u16 region ----
  u16* enc   = (u16*)(giE + (size_t)992*1536);         // (B,S,2U)
  u16* Xl    = enc + (size_t)2048*1024;                // 992x1856
  u16* Xsrc  = Xl + (size_t)992*1856;                  // 2048x320
  u16* WihF  = Xsrc + (size_t)2048*320;                // 1536x320
  u16* WihB  = WihF + (size_t)1536*320;
  u16* WihE  = WihB + (size_t)1536*320;
  u16* AttnW = WihE + (size_t)1536*320;                // 512x1024
  u16* Wenc  = AttnW + (size_t)512*1024;               // 2dir x 32ub x 49152
  u16* Wdc   = Wenc + (size_t)2*32*49152;              // 32ub x 49152
  u16* Wds   = Wdc + (size_t)32*49152;                 // 32ub x 49152
  u16* Wqp   = Wds + (size_t)32*49152;                 // 16ub x 32768
  u16* hbf   = Wqp + (size_t)16*32768;                 // 2par x 2dir x 32768
  u16* Actx  = hbf + (size_t)4*32768;                  // 32768
  u16* Ast   = Actx + 32768;                           // 2par x 32768
  u16* endu  = Ast + (size_t)2*32768;
  // ---- tail: gi (encoder-only) overlapped later by WfcB ----
  float* gi_f = (float*)endu;                          // 2048x1536
  float* gi_b = gi_f + (size_t)2048*1536;
  u16* WfcB  = endu;                                   // 30000x1856 (overlaps gi)
  u16* EmbT  = Xsrc;                                   // reuse after gi GEMMs

  k_init<<<3750, 256, 0, stream>>>(hF, out, Xl, (float*)hbf);
  k_embsrc<<<2560, 256, 0, stream>>>(emb_src, source, Xsrc);
  k_cvt<<<1536, 256, 0, stream>>>(eWih_f, 300, 0, 300, WihF, 320);
  k_cvt<<<1536, 256, 0, stream>>>(eWih_b, 300, 0, 300, WihB, 320);
  k_cvt<<<1536, 256, 0, stream>>>(dWih, 1324, 0, 300, WihE, 320);
  k_cvt<<<512, 256, 0, stream>>>(attn_W, 1536, 512, 1024, AttnW, 1024);
  // fragment-linear recurrent weights
  k_wprep<<<384, 256, 0, stream>>>(eWhh_f, 512, 0, 512, 3, 16, 16, 2, 98304, Wenc);
  k_wprep<<<384, 256, 0, stream>>>(eWhh_b, 512, 0, 512, 3, 16, 16, 2, 98304, Wenc + (size_t)32*49152);
  k_wprep<<<768, 256, 0, stream>>>(dWih, 1324, 300, 512, 3, 16, 32, 1, 196608, Wdc);
  k_wprep<<<384, 256, 0, stream>>>(dWhh, 512, 0, 512, 3, 16, 16, 2, 98304, Wds);
  k_wprep<<<128, 256, 0, stream>>>(attn_W, 1536, 0, 16, 2, 32, 16, 2, 32768, Wqp);
  // gi = Xsrc @ Wih^T + bih (both dirs)
  k_gemm_bf<<<dim3(16,12), 256, 0, stream>>>(Xsrc, 320, WihF, 320, ebih_f, gi_f, 1536, 0, 2048, 1536, 320);
  k_gemm_bf<<<dim3(16,12), 256, 0, stream>>>(Xsrc, 320, WihB, 320, ebih_b, gi_b, 1536, 0, 2048, 1536, 320);
  for(int t = 0; t < SS; t++)
    k_encs<<<64, 64, 0, stream>>>(t, gi_f, gi_b, Wenc, ebhh_f, ebhh_b, hF, hbf, enc);
  k_encfc<<<BB, 256, 0, stream>>>(hF, Wfc, bfc, st, Ast);
  k_gemm_bf<<<dim3(16,4), 256, 0, stream>>>(enc, 1024, AttnW, 1024, attn_b, P, 512, 0, 2048, 512, 1024);
  k_embT<<<1240, 256, 0, stream>>>(emb_trg, target, EmbT, Xl);
  k_gemm_bf<<<dim3(8,12), 256, 0, stream>>>(EmbT, 320, WihE, 320, dbih, giE, 1536, 0, 992, 1536, 320);
  for(int t = 0; t < TT-1; t++){
    int par = t & 1;
    k_dq<<<16, 64, 0, stream>>>(Ast + par*32768, Wqp, qG);
    k_dattn<<<BB, 1024, 0, stream>>>(t, qG, P, enc, Actx, Xl);
    k_dgru<<<32, 64, 0, stream>>>(t, st + par*16384, st + (par^1)*16384,
                                  Actx, Ast + par*32768, Ast + (par^1)*32768,
                                  Wdc, Wds, giE, dbhh, Xl);
  }
  // WfcB cvt deferred here: overlaps (dead) gi region
  k_cvt<<<30000, 256, 0, stream>>>(dWfc, 1836, 0, 1836, WfcB, 1856);
  k_gemm_lg<<<1920, 256, 0, stream>>>(Xl, 1856, WfcB, 1856, dbfc, out, VTT, 32, 992, VTT, 1856);
}